// Round 13
// baseline (575.920 us; speedup 1.0000x reference)
//
#include <hip/hip_runtime.h>

#define M_TOK 8192
#define N_OUT 4096
#define K_DIM 4096
#define NGROUPS 32          // K/128
#define K_TILES 128         // K/32

typedef __bf16 bf16x8 __attribute__((ext_vector_type(8)));
typedef __bf16 bf16x4 __attribute__((ext_vector_type(4)));
typedef float  f32x4  __attribute__((ext_vector_type(4)));

#define GLOBAL_CVP const __attribute__((address_space(1))) void*
#define LDS_VP __attribute__((address_space(3))) void*

// ---------------- prep: fused x-convert + w-dequant (concurrent) ----------
#define XBLOCKS 2048
#define WBLOCKS 1024
__global__ __launch_bounds__(256)
void prep_kernel(const float* __restrict__ x, __bf16* __restrict__ xb,
                 const int* __restrict__ wq, const float* __restrict__ scales,
                 const float* __restrict__ zeros, __bf16* __restrict__ wb) {
    if (blockIdx.x < XBLOCKS) {
        const size_t total = (size_t)M_TOK * K_DIM / 8;   // bf16x8 chunks
        for (size_t i = (size_t)blockIdx.x * blockDim.x + threadIdx.x; i < total;
             i += (size_t)XBLOCKS * blockDim.x) {
            const float4 v0 = ((const float4*)x)[2 * i];
            const float4 v1 = ((const float4*)x)[2 * i + 1];
            bf16x8 b;
            b[0] = (__bf16)v0.x; b[1] = (__bf16)v0.y; b[2] = (__bf16)v0.z; b[3] = (__bf16)v0.w;
            b[4] = (__bf16)v1.x; b[5] = (__bf16)v1.y; b[6] = (__bf16)v1.z; b[7] = (__bf16)v1.w;
            ((bf16x8*)xb)[i] = b;
        }
    } else {
        const size_t total = (size_t)N_OUT * K_DIM / 8;
        for (size_t i = (size_t)(blockIdx.x - XBLOCKS) * blockDim.x + threadIdx.x; i < total;
             i += (size_t)WBLOCKS * blockDim.x) {
            const int4 q0 = ((const int4*)wq)[2 * i];
            const int4 q1 = ((const int4*)wq)[2 * i + 1];
            const size_t e = i * 8;
            const int row = (int)(e >> 12);       // / 4096
            const int g   = ((int)e & 4095) >> 7; // group within row (8 | 128, no straddle)
            const float s = scales[row * NGROUPS + g];
            const float z = zeros [row * NGROUPS + g];
            bf16x8 b;
            b[0] = (__bf16)fmaf((float)q0.x, s, z);
            b[1] = (__bf16)fmaf((float)q0.y, s, z);
            b[2] = (__bf16)fmaf((float)q0.z, s, z);
            b[3] = (__bf16)fmaf((float)q0.w, s, z);
            b[4] = (__bf16)fmaf((float)q1.x, s, z);
            b[5] = (__bf16)fmaf((float)q1.y, s, z);
            b[6] = (__bf16)fmaf((float)q1.z, s, z);
            b[7] = (__bf16)fmaf((float)q1.w, s, z);
            ((bf16x8*)wb)[i] = b;
        }
    }
}

// ---------------- main: bf16 GEMM, B^T input, 256^2 tile, 4-slot ring ----
// A [M,K] row-major bf16, B [N,K] row-major bf16, out[M,N] fp32 = A.B^T + bias
//
//  - BM=BN=256, BK=32, 512 threads = 8 waves (2M x 4N), per-wave C = 128x64
//  - LDS: 4-slot ring per matrix (128 KB total), prefetch distance 2 tiles in
//    flight; vmcnt(4) steady state (T4: never 0 in main loop)
//  - one raw s_barrier per K-tile
//  - T2 swizzle (VERIFIED r4: SQ_LDS_BANK_CONFLICT 2.5e7 -> 0): LDS slot of
//    (row, q) is q ^ ((row>>1)&3); inverse applied to per-lane GLOBAL source
//    (linear global_load_lds dest), same involution on ds_read side.
//  - r5: register-level fragment double-buffer. While MFMA'ing tile t
//    (frags already in regs), issue the 12 ds_reads for tile t+1 -> the LDS
//    unit services reads UNDER the MFMA cluster instead of in a lockstep
//    burst. r4 accounting: 96 b128/CU/K-tile serviced serially = 1152 cyc
//    ~= measured 1280; MFMA only 310. Overlap should cut K-tile to
//    max(LDS, MFMA) + sync.
//    Race: FRAGS(t+1) drains at lgkmcnt before MFMAS(t+1), which precedes
//    the barrier preceding any STAGE that rewrites slot (t+1)&3 (4 half-
//    iters later). Named afA/afB sets (rule 20: no runtime indexing).
//  - setprio(1) around the 32-MFMA cluster (T5)
//  - bijective XCD swizzle: 512 wgs = 8 XCDs x 64 (T1)
__global__ __launch_bounds__(512, 2)
void gemm_bt256_kernel(const __bf16* __restrict__ A, const __bf16* __restrict__ B,
                       const float* __restrict__ bias, float* __restrict__ out) {
    __shared__ __bf16 As[4 * 8192];   // 64 KB: 4 slots of [256 rows][32 cols]
    __shared__ __bf16 Bs[4 * 8192];   // 64 KB

    const int tid  = threadIdx.x;
    const int wid  = tid >> 6;
    const int lane = tid & 63;

    // XCD-aware bijective swizzle (512 = 8 * 64, exact)
    const int s   = blockIdx.x;
    const int swz = (s & 7) * 64 + (s >> 3);
    const int m0  = (swz & 31) * 256;   // 32 M-blocks
    const int n0  = (swz >> 5) * 256;   // 16 N-blocks

    const int lrow  = lane & 15;
    const int quad  = lane >> 4;
    const int wmRow = (wid >> 2) * 128;  // wave's A-row base within tile
    const int wnRow = (wid & 3) * 64;    // wave's B-row base within tile
    // swizzled 16B-slot byte offset for fragment reads (involution of stage swz)
    const int sq = (quad ^ ((lrow >> 1) & 3)) * 8;

    // staging: lane l covers row (l>>2); global col-slot is pre-swizzled so
    // that the LINEAR LDS write lands data where the swizzled read expects it
    const int scol = ((lane & 3) ^ ((lane >> 3) & 3)) * 8;
    const __bf16* Abase = A + (size_t)(m0 + wid * 16 + (lane >> 2)) * K_DIM + scol;
    const __bf16* Bbase = B + (size_t)(n0 + wid * 16 + (lane >> 2)) * K_DIM + scol;

    f32x4 acc[8][4];
#pragma unroll
    for (int i = 0; i < 8; ++i)
#pragma unroll
        for (int j = 0; j < 4; ++j)
            acc[i][j] = (f32x4){0.f, 0.f, 0.f, 0.f};

    bf16x8 afA[8], bfA[4], afB[8], bfB[4];

#define STAGE(T)                                                                            \
    {                                                                                       \
        const int    _s  = (T) & 3;                                                         \
        const size_t _k  = (size_t)(T) * 32;                                                \
        const __bf16* _ga = Abase + _k;                                                     \
        const __bf16* _gb = Bbase + _k;                                                     \
        __bf16* _la = (__bf16*)As + _s * 8192 + wid * 512;                                  \
        __bf16* _lb = (__bf16*)Bs + _s * 8192 + wid * 512;                                  \
        __builtin_amdgcn_global_load_lds((GLOBAL_CVP)(_ga), (LDS_VP)(_la), 16, 0, 0);       \
        __builtin_amdgcn_global_load_lds((GLOBAL_CVP)(_ga + (size_t)128 * K_DIM),           \
                                         (LDS_VP)(_la + 4096), 16, 0, 0);                   \
        __builtin_amdgcn_global_load_lds((GLOBAL_CVP)(_gb), (LDS_VP)(_lb), 16, 0, 0);       \
        __builtin_amdgcn_global_load_lds((GLOBAL_CVP)(_gb + (size_t)128 * K_DIM),           \
                                         (LDS_VP)(_lb + 4096), 16, 0, 0);                   \
    }

#define FRAGS(AF, BF, T)                                                                    \
    {                                                                                       \
        const int _s = (T) & 3;                                                             \
        const __bf16* _As = (const __bf16*)As + _s * 8192;                                  \
        const __bf16* _Bs = (const __bf16*)Bs + _s * 8192;                                  \
        _Pragma("unroll")                                                                   \
        for (int _j = 0; _j < 4; ++_j)                                                      \
            BF[_j] = *(const bf16x8*)&_Bs[(wnRow + _j * 16 + lrow) * 32 + sq];              \
        _Pragma("unroll")                                                                   \
        for (int _i = 0; _i < 8; ++_i)                                                      \
            AF[_i] = *(const bf16x8*)&_As[(wmRow + _i * 16 + lrow) * 32 + sq];              \
    }

#define MFMAS(AF, BF)                                                                       \
    {                                                                                       \
        __builtin_amdgcn_s_setprio(1);                                                      \
        _Pragma("unroll")                                                                   \
        for (int _i = 0; _i < 8; ++_i)                                                      \
            _Pragma("unroll")                                                               \
            for (int _j = 0; _j < 4; ++_j)                                                  \
                acc[_i][_j] = __builtin_amdgcn_mfma_f32_16x16x32_bf16(AF[_i], BF[_j],       \
                                                                      acc[_i][_j], 0, 0, 0);\
        __builtin_amdgcn_s_setprio(0);                                                      \
    }

#define SYNC(VM)                                                                            \
    {                                                                                       \
        __builtin_amdgcn_sched_barrier(0);                                                  \
        asm volatile("s_waitcnt vmcnt(" #VM ")" ::: "memory");                              \
        __builtin_amdgcn_s_barrier();                                                       \
        __builtin_amdgcn_sched_barrier(0);                                                  \
    }

    // prologue: fill 3 ring slots; vmcnt(4) -> tiles 0,1 landed, 2 in flight
    STAGE(0); STAGE(1); STAGE(2);
    SYNC(4);
    FRAGS(afA, bfA, 0);

    // main loop (unroll-2): stage t+3, read frags t+1 (slot valid: landed at
    // prior SYNC(4) barrier), MFMA tile t from registers. vmcnt(4) keeps one
    // full tile in flight at all times (never drains in main loop).
    for (int t = 0; t < K_TILES - 6; t += 2) {
        STAGE(t + 3);
        FRAGS(afB, bfB, t + 1);
        MFMAS(afA, bfA);
        SYNC(4);
        STAGE(t + 4);
        FRAGS(afA, bfA, t + 2);
        MFMAS(afB, bfB);
        SYNC(4);
    }
    // epilogue peel: tiles 122..127 (staging ends at 127; ring drains)
    STAGE(125); FRAGS(afB, bfB, 123); MFMAS(afA, bfA); SYNC(4);   // t=122
    STAGE(126); FRAGS(afA, bfA, 124); MFMAS(afB, bfB); SYNC(4);   // t=123
    STAGE(127); FRAGS(afB, bfB, 125); MFMAS(afA, bfA); SYNC(4);   // t=124
    FRAGS(afA, bfA, 126); MFMAS(afB, bfB); SYNC(0);               // t=125
    FRAGS(afB, bfB, 127); MFMAS(afA, bfA);                        // t=126
    MFMAS(afB, bfB);                                              // t=127

#undef STAGE
#undef FRAGS
#undef MFMAS
#undef SYNC

    // epilogue: D row=(lane>>4)*4+reg, col=lane&15 (m89-verified) ; add bias
#pragma unroll
    for (int j = 0; j < 4; ++j) {
        const int col = n0 + wnRow + j * 16 + lrow;
        const float bv = bias[col];
#pragma unroll
        for (int i = 0; i < 8; ++i) {
            const int rowb = m0 + wmRow + i * 16 + quad * 4;
#pragma unroll
            for (int r = 0; r < 4; ++r)
                out[(size_t)(rowb + r) * N_OUT + col] = acc[i][j][r] + bv;
        }
    }
}

// ---------------- fallback (round-1 fused kernel, used if ws too small) ----
#define LDS_STRIDE 40
__global__ __launch_bounds__(256)
void qlinear_fused_kernel(const float* __restrict__ x,
                          const int*   __restrict__ wq,
                          const float* __restrict__ scales,
                          const float* __restrict__ zeros,
                          const float* __restrict__ bias,
                          float*       __restrict__ out)
{
    __shared__ __bf16 As[128 * LDS_STRIDE];
    __shared__ __bf16 Bs[128 * LDS_STRIDE];
    const int tid  = threadIdx.x;
    const int m0   = blockIdx.x * 128;
    const int n0   = blockIdx.y * 128;
    const int wave = tid >> 6;
    const int lane = tid & 63;
    const int wm   = (wave & 1) * 64;
    const int wn   = (wave >> 1) * 64;
    const int lrow = lane & 15;
    const int quad = lane >> 4;
    const int srow = tid >> 3;
    const int scol = (tid & 7) * 4;

    f32x4 acc[4][4];
#pragma unroll
    for (int i = 0; i < 4; i++)
#pragma unroll
        for (int j = 0; j < 4; j++)
            acc[i][j] = (f32x4){0.f, 0.f, 0.f, 0.f};

    for (int k0 = 0; k0 < K_DIM; k0 += 32) {
        const int g = k0 >> 7;
#pragma unroll
        for (int rr = 0; rr < 4; rr++) {
            const int row = srow + rr * 32;
            const float4 v = *(const float4*)(x + (size_t)(m0 + row) * K_DIM + k0 + scol);
            bf16x4 b;
            b[0] = (__bf16)v.x; b[1] = (__bf16)v.y;
            b[2] = (__bf16)v.z; b[3] = (__bf16)v.w;
            *(bf16x4*)&As[row * LDS_STRIDE + scol] = b;
        }
#pragma unroll
        for (int rr = 0; rr < 4; rr++) {
            const int row = srow + rr * 32;
            const int4 q = *(const int4*)(wq + (size_t)(n0 + row) * K_DIM + k0 + scol);
            const float s = scales[(n0 + row) * NGROUPS + g];
            const float z = zeros [(n0 + row) * NGROUPS + g];
            bf16x4 b;
            b[0] = (__bf16)fmaf((float)q.x, s, z);
            b[1] = (__bf16)fmaf((float)q.y, s, z);
            b[2] = (__bf16)fmaf((float)q.z, s, z);
            b[3] = (__bf16)fmaf((float)q.w, s, z);
            *(bf16x4*)&Bs[row * LDS_STRIDE + scol] = b;
        }
        __syncthreads();
        bf16x8 af[4], bfr[4];
#pragma unroll
        for (int i = 0; i < 4; i++) {
            af[i]  = *(const bf16x8*)&As[(wm + i * 16 + lrow) * LDS_STRIDE + quad * 8];
            bfr[i] = *(const bf16x8*)&Bs[(wn + i * 16 + lrow) * LDS_STRIDE + quad * 8];
        }
#pragma unroll
        for (int i = 0; i < 4; i++)
#pragma unroll
            for (int j = 0; j < 4; j++)
                acc[i][j] = __builtin_amdgcn_mfma_f32_16x16x32_bf16(af[i], bfr[j], acc[i][j], 0, 0, 0);
        __syncthreads();
    }
#pragma unroll
    for (int j = 0; j < 4; j++) {
        const int col = n0 + wn + j * 16 + lrow;
        const float bv = bias[col];
#pragma unroll
        for (int i = 0; i < 4; i++) {
            const int rowb = m0 + wm + i * 16 + quad * 4;
#pragma unroll
            for (int r = 0; r < 4; r++)
                out[(size_t)(rowb + r) * N_OUT + col] = acc[i][j][r] + bv;
        }
    }
}

extern "C" void kernel_launch(void* const* d_in, const int* in_sizes, int n_in,
                              void* d_out, int out_size, void* d_ws, size_t ws_size,
                              hipStream_t stream) {
    const float* x      = (const float*)d_in[0];
    const int*   wq     = (const int*)  d_in[1];
    const float* scales = (const float*)d_in[2];
    const float* zeros  = (const float*)d_in[3];
    const float* bias   = (const float*)d_in[4];
    float*       out    = (float*)d_out;

    const size_t xb_bytes = (size_t)M_TOK * K_DIM * 2;   // 67.1 MB
    const size_t wb_bytes = (size_t)N_OUT * K_DIM * 2;   // 33.6 MB

    if (ws_size >= xb_bytes + wb_bytes) {
        __bf16* xb = (__bf16*)d_ws;
        __bf16* wb = (__bf16*)((char*)d_ws + xb_bytes);
        prep_kernel<<<XBLOCKS + WBLOCKS, 256, 0, stream>>>(x, xb, wq, scales, zeros, wb);
        dim3 grid((M_TOK / 256) * (N_OUT / 256));   // 512 wgs, 1D for XCD swizzle
        gemm_bt256_kernel<<<grid, 512, 0, stream>>>(xb, wb, bias, out);
    } else {
        dim3 grid(M_TOK / 128, N_OUT / 128);
        qlinear_fused_kernel<<<grid, 256, 0, stream>>>(x, wq, scales, zeros, bias, out);
    }
}

// Round 15
// 569.353 us; speedup vs baseline: 1.0115x; 1.0115x over previous
//
#include <hip/hip_runtime.h>

#define M_TOK 8192
#define N_OUT 4096
#define K_DIM 4096
#define NGROUPS 32          // K/128
#define KT64 64             // K-tiles of BK=64

typedef __bf16 bf16x8 __attribute__((ext_vector_type(8)));
typedef __bf16 bf16x4 __attribute__((ext_vector_type(4)));
typedef float  f32x4  __attribute__((ext_vector_type(4)));

#define GLOBAL_CVP const __attribute__((address_space(1))) void*
#define LDS_VP __attribute__((address_space(3))) void*

// ---------------- prep: fused x-convert + w-dequant (concurrent) ----------
#define XBLOCKS 2048
#define WBLOCKS 1024
__global__ __launch_bounds__(256)
void prep_kernel(const float* __restrict__ x, __bf16* __restrict__ xb,
                 const int* __restrict__ wq, const float* __restrict__ scales,
                 const float* __restrict__ zeros, __bf16* __restrict__ wb) {
    if (blockIdx.x < XBLOCKS) {
        const size_t total = (size_t)M_TOK * K_DIM / 8;   // bf16x8 chunks
        for (size_t i = (size_t)blockIdx.x * blockDim.x + threadIdx.x; i < total;
             i += (size_t)XBLOCKS * blockDim.x) {
            const float4 v0 = ((const float4*)x)[2 * i];
            const float4 v1 = ((const float4*)x)[2 * i + 1];
            bf16x8 b;
            b[0] = (__bf16)v0.x; b[1] = (__bf16)v0.y; b[2] = (__bf16)v0.z; b[3] = (__bf16)v0.w;
            b[4] = (__bf16)v1.x; b[5] = (__bf16)v1.y; b[6] = (__bf16)v1.z; b[7] = (__bf16)v1.w;
            ((bf16x8*)xb)[i] = b;
        }
    } else {
        const size_t total = (size_t)N_OUT * K_DIM / 8;
        for (size_t i = (size_t)(blockIdx.x - XBLOCKS) * blockDim.x + threadIdx.x; i < total;
             i += (size_t)WBLOCKS * blockDim.x) {
            const int4 q0 = ((const int4*)wq)[2 * i];
            const int4 q1 = ((const int4*)wq)[2 * i + 1];
            const size_t e = i * 8;
            const int row = (int)(e >> 12);       // / 4096
            const int g   = ((int)e & 4095) >> 7; // group within row
            const float s = scales[row * NGROUPS + g];
            const float z = zeros [row * NGROUPS + g];
            bf16x8 b;
            b[0] = (__bf16)fmaf((float)q0.x, s, z);
            b[1] = (__bf16)fmaf((float)q0.y, s, z);
            b[2] = (__bf16)fmaf((float)q0.z, s, z);
            b[3] = (__bf16)fmaf((float)q0.w, s, z);
            b[4] = (__bf16)fmaf((float)q1.x, s, z);
            b[5] = (__bf16)fmaf((float)q1.y, s, z);
            b[6] = (__bf16)fmaf((float)q1.z, s, z);
            b[7] = (__bf16)fmaf((float)q1.w, s, z);
            ((bf16x8*)wb)[i] = b;
        }
    }
}

// ---------------- main: 256^2 tile, BK=64, m201-style 4-phase/K-tile ------
// A [M,K] bf16, B [N,K] bf16, out[M,N] f32 = A.B^T + bias.
//
// Geometry: 512 thr = 8 waves (2M x 4N), per-wave C = 128x64, acc[8][4].
// LDS 128 KB: As/Bs = [2 buf][2 half][128 rows][64 cols] bf16 (32K el each).
// Swizzle (both-sides involution, rule 21): 16B granule g of row r stored at
//   g ^ (r&7). Read granule (ks*4+quad) ^ (lrow&7) -> per 8-lane service
//   group all 8 granules distinct -> ZERO bank conflict (verified technique
//   r4: 2.5e7 -> 0 with same construction at BK=32).
// Per K-tile t (buf b=t&1), 4 phases x {ds_reads; 1 half-tile stage; barrier;
// lgkmcnt(0); setprio(1); 16 MFMA; setprio(0); barrier}  [m201/T3+T4 form]:
//   P1: rd af(mh0) 8 + bfA(nh0) 4; stage A0(t+1)->buf b^1; MFMA Q00
//   P2: rd bfB(nh1) 4;             stage A1(t+1)->buf b^1; MFMA Q01
//   P3: rd af(mh1) 8;              stage B0(t+2)->buf b;   MFMA Q11
//   P4: (bfA reused, no reads);    stage B1(t+2)->buf b;   MFMA Q10
//       then vmcnt(4) + barrier  [counted, never 0 mid-loop: T4]
// Race edges: buf b^1 has NO readers during compute(t); B-halves of buf b are
// LDS-read-complete at P2-barrier (P4 uses bfA registers), so P3/P4 B-stages
// are safe; A(t+1)/B(t+2) landing is guaranteed by vmcnt(4) at P4 (youngest
// 4 loads = this iteration's B-stages; all older have landed) + barrier.
// Prologue: A0,A1,B0,B1(0), B0,B1(1); vmcnt(4); barrier. Tail: t=62 stages
// A(63) with vmcnt(0); t=63 stages nothing.
__global__ __launch_bounds__(512, 2)
void gemm_bt256_kernel(const __bf16* __restrict__ A, const __bf16* __restrict__ B,
                       const float* __restrict__ bias, float* __restrict__ out) {
    __shared__ __bf16 As[32768];   // 64 KB
    __shared__ __bf16 Bs[32768];   // 64 KB

    const int tid  = threadIdx.x;
    const int wid  = tid >> 6;
    const int lane = tid & 63;

    // XCD-aware bijective swizzle (512 = 8 * 64, exact)
    const int s   = blockIdx.x;
    const int swz = (s & 7) * 64 + (s >> 3);
    const int m0  = (swz & 31) * 256;   // 32 M-blocks
    const int n0  = (swz >> 5) * 256;   // 16 N-blocks

    const int lrow  = lane & 15;
    const int quad  = lane >> 4;
    const int wmRow = (wid >> 2) * 128;
    const int wnRow = (wid & 3) * 64;

    // fragment-read granule offsets (elements), ks=0/1 halves of BK=64
    const int g0 = ((quad)     ^ (lrow & 7)) * 8;
    const int g1 = ((quad + 4) ^ (lrow & 7)) * 8;

    // staging per-lane constants: lane covers row (lane>>3) of an 8-row
    // stripe, source granule pre-swizzled so the LINEAR LDS write lands
    // where the swizzled read expects it (rule 21 both-sides involution)
    const int srow = lane >> 3;                       // 0..7
    const int scol = ((lane & 7) ^ srow) * 8;         // element col
    const __bf16* Asrc = A + (size_t)(m0 + wid * 16 + srow) * K_DIM + scol;
    const __bf16* Bsrc = B + (size_t)(n0 + wid * 16 + srow) * K_DIM + scol;
    const int ldst = wid * 1024 + lane * 8;           // element offset in half

    // fragment-read bases: wave's A-half and B-half
    const __bf16* AhB = As + (wid >> 2) * 8192;
    const __bf16* BhB = Bs + ((wid & 3) >> 1) * 8192;
    const int lbB = ((wid & 3) & 1) * 64;             // local B row base

    f32x4 acc[8][4];
#pragma unroll
    for (int i = 0; i < 8; ++i)
#pragma unroll
        for (int j = 0; j < 4; ++j)
            acc[i][j] = (f32x4){0.f, 0.f, 0.f, 0.f};

    bf16x8 af[8], bfA[4], bfB[4];

#define SGA(TT, H)                                                                          \
    {                                                                                       \
        __bf16* _d = (__bf16*)As + ((TT) & 1) * 16384 + (H) * 8192 + ldst;                  \
        const __bf16* _g = Asrc + (size_t)((H) * 128) * K_DIM + (size_t)(TT) * 64;          \
        __builtin_amdgcn_global_load_lds((GLOBAL_CVP)_g, (LDS_VP)_d, 16, 0, 0);             \
        __builtin_amdgcn_global_load_lds((GLOBAL_CVP)(_g + (size_t)8 * K_DIM),              \
                                         (LDS_VP)(_d + 512), 16, 0, 0);                     \
    }
#define SGB(TT, H)                                                                          \
    {                                                                                       \
        __bf16* _d = (__bf16*)Bs + ((TT) & 1) * 16384 + (H) * 8192 + ldst;                  \
        const __bf16* _g = Bsrc + (size_t)((H) * 128) * K_DIM + (size_t)(TT) * 64;          \
        __builtin_amdgcn_global_load_lds((GLOBAL_CVP)_g, (LDS_VP)_d, 16, 0, 0);             \
        __builtin_amdgcn_global_load_lds((GLOBAL_CVP)(_g + (size_t)8 * K_DIM),              \
                                         (LDS_VP)(_d + 512), 16, 0, 0);                     \
    }
#define RDA(MH)                                                                             \
    _Pragma("unroll") for (int _i = 0; _i < 4; ++_i) {                                      \
        af[_i]     = *(const bf16x8*)&Ab[((MH) * 64 + _i * 16 + lrow) * 64 + g0];           \
        af[4 + _i] = *(const bf16x8*)&Ab[((MH) * 64 + _i * 16 + lrow) * 64 + g1];           \
    }
#define RDB(NH, BF)                                                                         \
    _Pragma("unroll") for (int _j = 0; _j < 2; ++_j) {                                      \
        BF[_j]     = *(const bf16x8*)&Bb[(lbB + (NH) * 32 + _j * 16 + lrow) * 64 + g0];     \
        BF[2 + _j] = *(const bf16x8*)&Bb[(lbB + (NH) * 32 + _j * 16 + lrow) * 64 + g1];     \
    }
#define MF16(MH, NH, BF)                                                                    \
    __builtin_amdgcn_s_setprio(1);                                                          \
    _Pragma("unroll") for (int _i = 0; _i < 4; ++_i)                                        \
    _Pragma("unroll") for (int _j = 0; _j < 2; ++_j) {                                      \
        acc[(MH)*4+_i][(NH)*2+_j] = __builtin_amdgcn_mfma_f32_16x16x32_bf16(                \
            af[_i], BF[_j], acc[(MH)*4+_i][(NH)*2+_j], 0, 0, 0);                            \
        acc[(MH)*4+_i][(NH)*2+_j] = __builtin_amdgcn_mfma_f32_16x16x32_bf16(                \
            af[4+_i], BF[2+_j], acc[(MH)*4+_i][(NH)*2+_j], 0, 0, 0);                        \
    }                                                                                       \
    __builtin_amdgcn_s_setprio(0);
#define BAR                                                                                 \
    {                                                                                       \
        __builtin_amdgcn_sched_barrier(0);                                                  \
        __builtin_amdgcn_s_barrier();                                                       \
        __builtin_amdgcn_sched_barrier(0);                                                  \
    }
#define BARLG                                                                               \
    {                                                                                       \
        __builtin_amdgcn_sched_barrier(0);                                                  \
        __builtin_amdgcn_s_barrier();                                                       \
        asm volatile("s_waitcnt lgkmcnt(0)" ::: "memory");                                  \
        __builtin_amdgcn_sched_barrier(0);                                                  \
    }
#define KITER(T, SA, SB, VMQ)                                                               \
    {                                                                                       \
        const int _b = (T) & 1;                                                             \
        const __bf16* Ab = AhB + _b * 16384;                                                \
        const __bf16* Bb = BhB + _b * 16384;                                                \
        /* P1 */                                                                            \
        RDA(0); RDB(0, bfA);                                                                \
        if (SA) SGA((T) + 1, 0);                                                            \
        asm volatile("s_waitcnt lgkmcnt(8)" ::: "memory");                                  \
        BARLG; MF16(0, 0, bfA); BAR;                                                        \
        /* P2 */                                                                            \
        RDB(1, bfB);                                                                        \
        if (SA) SGA((T) + 1, 1);                                                            \
        BARLG; MF16(0, 1, bfB); BAR;                                                        \
        /* P3 */                                                                            \
        RDA(1);                                                                             \
        if (SB) SGB((T) + 2, 0);                                                            \
        BARLG; MF16(1, 1, bfB); BAR;                                                        \
        /* P4 (bfA reused from registers; no LDS reads) */                                  \
        if (SB) SGB((T) + 2, 1);                                                            \
        BAR; MF16(1, 0, bfA);                                                               \
        __builtin_amdgcn_sched_barrier(0);                                                  \
        asm volatile("s_waitcnt vmcnt(" #VMQ ")" ::: "memory");                             \
        __builtin_amdgcn_s_barrier();                                                       \
        __builtin_amdgcn_sched_barrier(0);                                                  \
    }

    // prologue: K-tile 0 fully + B halves of K-tile 1 (A(1) staged in t=0)
    SGA(0, 0); SGA(0, 1); SGB(0, 0); SGB(0, 1); SGB(1, 0); SGB(1, 1);
    asm volatile("s_waitcnt vmcnt(4)" ::: "memory");
    __builtin_amdgcn_s_barrier();

#pragma unroll 1
    for (int t = 0; t < KT64 - 2; ++t) {
        KITER(t, 1, 1, 4);
    }
    KITER(KT64 - 2, 1, 0, 0);   // t=62: stages A(63), drain all
    KITER(KT64 - 1, 0, 0, 0);   // t=63: no stages

#undef SGA
#undef SGB
#undef RDA
#undef RDB
#undef MF16
#undef BAR
#undef BARLG
#undef KITER

    // epilogue: D row=(lane>>4)*4+reg, col=lane&15 (m89-verified) ; add bias
#pragma unroll
    for (int j = 0; j < 4; ++j) {
        const int col = n0 + wnRow + j * 16 + lrow;
        const float bv = bias[col];
#pragma unroll
        for (int i = 0; i < 8; ++i) {
            const int rowb = m0 + wmRow + i * 16 + quad * 4;
#pragma unroll
            for (int r = 0; r < 4; ++r)
                out[(size_t)(rowb + r) * N_OUT + col] = acc[i][j][r] + bv;
        }
    }
}

// ---------------- fallback (round-1 fused kernel, used if ws too small) ----
#define LDS_STRIDE 40
__global__ __launch_bounds__(256)
void qlinear_fused_kernel(const float* __restrict__ x,
                          const int*   __restrict__ wq,
                          const float* __restrict__ scales,
                          const float* __restrict__ zeros,
                          const float* __restrict__ bias,
                          float*       __restrict__ out)
{
    __shared__ __bf16 As[128 * LDS_STRIDE];
    __shared__ __bf16 Bs[128 * LDS_STRIDE];
    const int tid  = threadIdx.x;
    const int m0   = blockIdx.x * 128;
    const int n0   = blockIdx.y * 128;
    const int wave = tid >> 6;
    const int lane = tid & 63;
    const int wm   = (wave & 1) * 64;
    const int wn   = (wave >> 1) * 64;
    const int lrow = lane & 15;
    const int quad = lane >> 4;
    const int srow = tid >> 3;
    const int scol = (tid & 7) * 4;

    f32x4 acc[4][4];
#pragma unroll
    for (int i = 0; i < 4; i++)
#pragma unroll
        for (int j = 0; j < 4; j++)
            acc[i][j] = (f32x4){0.f, 0.f, 0.f, 0.f};

    for (int k0 = 0; k0 < K_DIM; k0 += 32) {
        const int g = k0 >> 7;
#pragma unroll
        for (int rr = 0; rr < 4; rr++) {
            const int row = srow + rr * 32;
            const float4 v = *(const float4*)(x + (size_t)(m0 + row) * K_DIM + k0 + scol);
            bf16x4 b;
            b[0] = (__bf16)v.x; b[1] = (__bf16)v.y;
            b[2] = (__bf16)v.z; b[3] = (__bf16)v.w;
            *(bf16x4*)&As[row * LDS_STRIDE + scol] = b;
        }
#pragma unroll
        for (int rr = 0; rr < 4; rr++) {
            const int row = srow + rr * 32;
            const int4 q = *(const int4*)(wq + (size_t)(n0 + row) * K_DIM + k0 + scol);
            const float s = scales[(n0 + row) * NGROUPS + g];
            const float z = zeros [(n0 + row) * NGROUPS + g];
            bf16x4 b;
            b[0] = (__bf16)fmaf((float)q.x, s, z);
            b[1] = (__bf16)fmaf((float)q.y, s, z);
            b[2] = (__bf16)fmaf((float)q.z, s, z);
            b[3] = (__bf16)fmaf((float)q.w, s, z);
            *(bf16x4*)&Bs[row * LDS_STRIDE + scol] = b;
        }
        __syncthreads();
        bf16x8 af[4], bfr[4];
#pragma unroll
        for (int i = 0; i < 4; i++) {
            af[i]  = *(const bf16x8*)&As[(wm + i * 16 + lrow) * LDS_STRIDE + quad * 8];
            bfr[i] = *(const bf16x8*)&Bs[(wn + i * 16 + lrow) * LDS_STRIDE + quad * 8];
        }
#pragma unroll
        for (int i = 0; i < 4; i++)
#pragma unroll
            for (int j = 0; j < 4; j++)
                acc[i][j] = __builtin_amdgcn_mfma_f32_16x16x32_bf16(af[i], bfr[j], acc[i][j], 0, 0, 0);
        __syncthreads();
    }
#pragma unroll
    for (int j = 0; j < 4; j++) {
        const int col = n0 + wn + j * 16 + lrow;
        const float bv = bias[col];
#pragma unroll
        for (int i = 0; i < 4; i++) {
            const int rowb = m0 + wm + i * 16 + quad * 4;
#pragma unroll
            for (int r = 0; r < 4; r++)
                out[(size_t)(rowb + r) * N_OUT + col] = acc[i][j][r] + bv;
        }
    }
}

extern "C" void kernel_launch(void* const* d_in, const int* in_sizes, int n_in,
                              void* d_out, int out_size, void* d_ws, size_t ws_size,
                              hipStream_t stream) {
    const float* x      = (const float*)d_in[0];
    const int*   wq     = (const int*)  d_in[1];
    const float* scales = (const float*)d_in[2];
    const float* zeros  = (const float*)d_in[3];
    const float* bias   = (const float*)d_in[4];
    float*       out    = (float*)d_out;

    const size_t xb_bytes = (size_t)M_TOK * K_DIM * 2;   // 67.1 MB
    const size_t wb_bytes = (size_t)N_OUT * K_DIM * 2;   // 33.6 MB

    if (ws_size >= xb_bytes + wb_bytes) {
        __bf16* xb = (__bf16*)d_ws;
        __bf16* wb = (__bf16*)((char*)d_ws + xb_bytes);
        prep_kernel<<<XBLOCKS + WBLOCKS, 256, 0, stream>>>(x, xb, wq, scales, zeros, wb);
        dim3 grid((M_TOK / 256) * (N_OUT / 256));   // 512 wgs, 1D for XCD swizzle
        gemm_bt256_kernel<<<grid, 512, 0, stream>>>(xb, wb, bias, out);
    } else {
        dim3 grid(M_TOK / 128, N_OUT / 128);
        qlinear_fused_kernel<<<grid, 256, 0, stream>>>(x, wq, scales, zeros, bias, out);
    }
}

// Round 18
// 542.932 us; speedup vs baseline: 1.0608x; 1.0487x over previous
//
#include <hip/hip_runtime.h>

#define M_TOK 8192
#define N_OUT 4096
#define K_DIM 4096
#define NGROUPS 32          // K/128
#define K_TILES 128         // K/32

typedef __bf16 bf16x8 __attribute__((ext_vector_type(8)));
typedef __bf16 bf16x4 __attribute__((ext_vector_type(4)));
typedef float  f32x4  __attribute__((ext_vector_type(4)));

#define GLOBAL_CVP const __attribute__((address_space(1))) void*
#define LDS_VP __attribute__((address_space(3))) void*

// ---------------- prep: fused x-convert + w-dequant (concurrent) ----------
#define XBLOCKS 2048
#define WBLOCKS 1024
__global__ __launch_bounds__(256)
void prep_kernel(const float* __restrict__ x, __bf16* __restrict__ xb,
                 const int* __restrict__ wq, const float* __restrict__ scales,
                 const float* __restrict__ zeros, __bf16* __restrict__ wb) {
    if (blockIdx.x < XBLOCKS) {
        const size_t total = (size_t)M_TOK * K_DIM / 8;   // bf16x8 chunks
        for (size_t i = (size_t)blockIdx.x * blockDim.x + threadIdx.x; i < total;
             i += (size_t)XBLOCKS * blockDim.x) {
            const float4 v0 = ((const float4*)x)[2 * i];
            const float4 v1 = ((const float4*)x)[2 * i + 1];
            bf16x8 b;
            b[0] = (__bf16)v0.x; b[1] = (__bf16)v0.y; b[2] = (__bf16)v0.z; b[3] = (__bf16)v0.w;
            b[4] = (__bf16)v1.x; b[5] = (__bf16)v1.y; b[6] = (__bf16)v1.z; b[7] = (__bf16)v1.w;
            ((bf16x8*)xb)[i] = b;
        }
    } else {
        const size_t total = (size_t)N_OUT * K_DIM / 8;
        for (size_t i = (size_t)(blockIdx.x - XBLOCKS) * blockDim.x + threadIdx.x; i < total;
             i += (size_t)WBLOCKS * blockDim.x) {
            const int4 q0 = ((const int4*)wq)[2 * i];
            const int4 q1 = ((const int4*)wq)[2 * i + 1];
            const size_t e = i * 8;
            const int row = (int)(e >> 12);       // / 4096
            const int g   = ((int)e & 4095) >> 7; // group within row (8 | 128, no straddle)
            const float s = scales[row * NGROUPS + g];
            const float z = zeros [row * NGROUPS + g];
            bf16x8 b;
            b[0] = (__bf16)fmaf((float)q0.x, s, z);
            b[1] = (__bf16)fmaf((float)q0.y, s, z);
            b[2] = (__bf16)fmaf((float)q0.z, s, z);
            b[3] = (__bf16)fmaf((float)q0.w, s, z);
            b[4] = (__bf16)fmaf((float)q1.x, s, z);
            b[5] = (__bf16)fmaf((float)q1.y, s, z);
            b[6] = (__bf16)fmaf((float)q1.z, s, z);
            b[7] = (__bf16)fmaf((float)q1.w, s, z);
            ((bf16x8*)wb)[i] = b;
        }
    }
}

// ---------------- main: bf16 GEMM, B^T input, 256^2 tile, 4-slot ring ----
// A [M,K] row-major bf16, B [N,K] row-major bf16, out[M,N] fp32 = A.B^T + bias
//
// r16 change vs the r4-MEASURED kernel (273 us GEMM, MfmaUtil 44.5, confl 0):
//   TWO K-tiles per barrier window (was one). r15's post-mortem accounting:
//   r4 residual ~1300 cyc/tile = sync cost (~600) + lockstep LDS burst; the
//   4-phase structure (8 syncs/BK64) REGRESSED to 313 us, so MORE syncs hurt
//   -> go the other way: HALVE syncs on the verified template.
// Window W(t), t even: STAGE(t+2); STAGE(t+3); KBODY(t); KBODY(t+1);
//   vmcnt(0)+barrier.
//   - slots: computing pair {t&3,(t+1)&3}, staging pair {(t+2)&3,(t+3)&3} =
//     complementary -> no in-window collision.
//   - WAR: slot (t+2)&3 last read as tile t-2 in the PREVIOUS window, all
//     waves done before that window's end barrier.
//   - RAW: vmcnt(0)+barrier at window end -> (t+2,t+3) landed+visible. The
//     drain is ~free: those loads were issued a full window (~3400 cyc)
//     earlier >> 900-cyc HBM latency.
//  - T2 swizzle (VERIFIED r4: SQ_LDS_BANK_CONFLICT 2.5e7 -> 0): LDS slot of
//    (row, q) is q ^ ((row>>1)&3); inverse applied to per-lane GLOBAL source
//    (linear global_load_lds dest), same involution on ds_read side.
//  - setprio(1) around the 32-MFMA cluster (T5)
//  - bijective XCD swizzle: 512 wgs = 8 XCDs x 64 (T1)
__global__ __launch_bounds__(512, 2)
void gemm_bt256_kernel(const __bf16* __restrict__ A, const __bf16* __restrict__ B,
                       const float* __restrict__ bias, float* __restrict__ out) {
    __shared__ __bf16 As[4 * 8192];   // 64 KB: 4 slots of [256 rows][32 cols]
    __shared__ __bf16 Bs[4 * 8192];   // 64 KB

    const int tid  = threadIdx.x;
    const int wid  = tid >> 6;
    const int lane = tid & 63;

    // XCD-aware bijective swizzle (512 = 8 * 64, exact)
    const int s   = blockIdx.x;
    const int swz = (s & 7) * 64 + (s >> 3);
    const int m0  = (swz & 31) * 256;   // 32 M-blocks
    const int n0  = (swz >> 5) * 256;   // 16 N-blocks

    const int lrow  = lane & 15;
    const int quad  = lane >> 4;
    const int wmRow = (wid >> 2) * 128;  // wave's A-row base within tile
    const int wnRow = (wid & 3) * 64;    // wave's B-row base within tile
    // swizzled 16B-slot byte offset for fragment reads (involution of stage swz)
    const int sq = (quad ^ ((lrow >> 1) & 3)) * 8;

    // staging: lane l covers row (l>>2); global col-slot is pre-swizzled so
    // that the LINEAR LDS write lands data where the swizzled read expects it
    const int scol = ((lane & 3) ^ ((lane >> 3) & 3)) * 8;
    const __bf16* Abase = A + (size_t)(m0 + wid * 16 + (lane >> 2)) * K_DIM + scol;
    const __bf16* Bbase = B + (size_t)(n0 + wid * 16 + (lane >> 2)) * K_DIM + scol;

    f32x4 acc[8][4];
#pragma unroll
    for (int i = 0; i < 8; ++i)
#pragma unroll
        for (int j = 0; j < 4; ++j)
            acc[i][j] = (f32x4){0.f, 0.f, 0.f, 0.f};

#define STAGE(T)                                                                            \
    {                                                                                       \
        const int    _s  = (T) & 3;                                                         \
        const size_t _k  = (size_t)(T) * 32;                                                \
        const __bf16* _ga = Abase + _k;                                                     \
        const __bf16* _gb = Bbase + _k;                                                     \
        __bf16* _la = (__bf16*)As + _s * 8192 + wid * 512;                                  \
        __bf16* _lb = (__bf16*)Bs + _s * 8192 + wid * 512;                                  \
        __builtin_amdgcn_global_load_lds((GLOBAL_CVP)(_ga), (LDS_VP)(_la), 16, 0, 0);       \
        __builtin_amdgcn_global_load_lds((GLOBAL_CVP)(_ga + (size_t)128 * K_DIM),           \
                                         (LDS_VP)(_la + 4096), 16, 0, 0);                   \
        __builtin_amdgcn_global_load_lds((GLOBAL_CVP)(_gb), (LDS_VP)(_lb), 16, 0, 0);       \
        __builtin_amdgcn_global_load_lds((GLOBAL_CVP)(_gb + (size_t)128 * K_DIM),           \
                                         (LDS_VP)(_lb + 4096), 16, 0, 0);                   \
    }

#define KBODY(T)                                                                            \
    {                                                                                       \
        const int _s = (T) & 3;                                                             \
        const __bf16* _As = (const __bf16*)As + _s * 8192;                                  \
        const __bf16* _Bs = (const __bf16*)Bs + _s * 8192;                                  \
        bf16x8 _af[8], _bf[4];                                                              \
        _Pragma("unroll")                                                                   \
        for (int _j = 0; _j < 4; ++_j)                                                      \
            _bf[_j] = *(const bf16x8*)&_Bs[(wnRow + _j * 16 + lrow) * 32 + sq];             \
        _Pragma("unroll")                                                                   \
        for (int _i = 0; _i < 8; ++_i)                                                      \
            _af[_i] = *(const bf16x8*)&_As[(wmRow + _i * 16 + lrow) * 32 + sq];             \
        __builtin_amdgcn_s_setprio(1);                                                      \
        _Pragma("unroll")                                                                   \
        for (int _i = 0; _i < 8; ++_i)                                                      \
            _Pragma("unroll")                                                               \
            for (int _j = 0; _j < 4; ++_j)                                                  \
                acc[_i][_j] = __builtin_amdgcn_mfma_f32_16x16x32_bf16(_af[_i], _bf[_j],     \
                                                                      acc[_i][_j], 0, 0, 0);\
        __builtin_amdgcn_s_setprio(0);                                                      \
    }

#define SYNC0                                                                               \
    {                                                                                       \
        __builtin_amdgcn_sched_barrier(0);                                                  \
        asm volatile("s_waitcnt vmcnt(0)" ::: "memory");                                    \
        __builtin_amdgcn_s_barrier();                                                       \
        __builtin_amdgcn_sched_barrier(0);                                                  \
    }

    // prologue: stage window 0 (tiles 0,1), drain once (one-time ~900 cyc)
    STAGE(0); STAGE(1);
    SYNC0;

    // main loop: one sync per TWO K-tiles. Stage next window first (issue-
    // early), then compute both tiles of this window, then drain+barrier.
#pragma unroll 2
    for (int t = 0; t < K_TILES - 2; t += 2) {
        STAGE(t + 2);
        STAGE(t + 3);
        KBODY(t);
        KBODY(t + 1);
        SYNC0;
    }
    // final window: tiles 126,127 already staged and landed
    KBODY(K_TILES - 2);
    KBODY(K_TILES - 1);

#undef STAGE
#undef KBODY
#undef SYNC0

    // epilogue: D row=(lane>>4)*4+reg, col=lane&15 (m89-verified) ; add bias
#pragma unroll
    for (int j = 0; j < 4; ++j) {
        const int col = n0 + wnRow + j * 16 + lrow;
        const float bv = bias[col];
#pragma unroll
        for (int i = 0; i < 8; ++i) {
            const int rowb = m0 + wmRow + i * 16 + quad * 4;
#pragma unroll
            for (int r = 0; r < 4; ++r)
                out[(size_t)(rowb + r) * N_OUT + col] = acc[i][j][r] + bv;
        }
    }
}

// ---------------- fallback (round-1 fused kernel, used if ws too small) ----
#define LDS_STRIDE 40
__global__ __launch_bounds__(256)
void qlinear_fused_kernel(const float* __restrict__ x,
                          const int*   __restrict__ wq,
                          const float* __restrict__ scales,
                          const float* __restrict__ zeros,
                          const float* __restrict__ bias,
                          float*       __restrict__ out)
{
    __shared__ __bf16 As[128 * LDS_STRIDE];
    __shared__ __bf16 Bs[128 * LDS_STRIDE];
    const int tid  = threadIdx.x;
    const int m0   = blockIdx.x * 128;
    const int n0   = blockIdx.y * 128;
    const int wave = tid >> 6;
    const int lane = tid & 63;
    const int wm   = (wave & 1) * 64;
    const int wn   = (wave >> 1) * 64;
    const int lrow = lane & 15;
    const int quad = lane >> 4;
    const int srow = tid >> 3;
    const int scol = (tid & 7) * 4;

    f32x4 acc[4][4];
#pragma unroll
    for (int i = 0; i < 4; i++)
#pragma unroll
        for (int j = 0; j < 4; j++)
            acc[i][j] = (f32x4){0.f, 0.f, 0.f, 0.f};

    for (int k0 = 0; k0 < K_DIM; k0 += 32) {
        const int g = k0 >> 7;
#pragma unroll
        for (int rr = 0; rr < 4; rr++) {
            const int row = srow + rr * 32;
            const float4 v = *(const float4*)(x + (size_t)(m0 + row) * K_DIM + k0 + scol);
            bf16x4 b;
            b[0] = (__bf16)v.x; b[1] = (__bf16)v.y;
            b[2] = (__bf16)v.z; b[3] = (__bf16)v.w;
            *(bf16x4*)&As[row * LDS_STRIDE + scol] = b;
        }
#pragma unroll
        for (int rr = 0; rr < 4; rr++) {
            const int row = srow + rr * 32;
            const int4 q = *(const int4*)(wq + (size_t)(n0 + row) * K_DIM + k0 + scol);
            const float s = scales[(n0 + row) * NGROUPS + g];
            const float z = zeros [(n0 + row) * NGROUPS + g];
            bf16x4 b;
            b[0] = (__bf16)fmaf((float)q.x, s, z);
            b[1] = (__bf16)fmaf((float)q.y, s, z);
            b[2] = (__bf16)fmaf((float)q.z, s, z);
            b[3] = (__bf16)fmaf((float)q.w, s, z);
            *(bf16x4*)&Bs[row * LDS_STRIDE + scol] = b;
        }
        __syncthreads();
        bf16x8 af[4], bfr[4];
#pragma unroll
        for (int i = 0; i < 4; i++) {
            af[i]  = *(const bf16x8*)&As[(wm + i * 16 + lrow) * LDS_STRIDE + quad * 8];
            bfr[i] = *(const bf16x8*)&Bs[(wn + i * 16 + lrow) * LDS_STRIDE + quad * 8];
        }
#pragma unroll
        for (int i = 0; i < 4; i++)
#pragma unroll
            for (int j = 0; j < 4; j++)
                acc[i][j] = __builtin_amdgcn_mfma_f32_16x16x32_bf16(af[i], bfr[j], acc[i][j], 0, 0, 0);
        __syncthreads();
    }
#pragma unroll
    for (int j = 0; j < 4; j++) {
        const int col = n0 + wn + j * 16 + lrow;
        const float bv = bias[col];
#pragma unroll
        for (int i = 0; i < 4; i++) {
            const int rowb = m0 + wm + i * 16 + quad * 4;
#pragma unroll
            for (int r = 0; r < 4; r++)
                out[(size_t)(rowb + r) * N_OUT + col] = acc[i][j][r] + bv;
        }
    }
}

extern "C" void kernel_launch(void* const* d_in, const int* in_sizes, int n_in,
                              void* d_out, int out_size, void* d_ws, size_t ws_size,
                              hipStream_t stream) {
    const float* x      = (const float*)d_in[0];
    const int*   wq     = (const int*)  d_in[1];
    const float* scales = (const float*)d_in[2];
    const float* zeros  = (const float*)d_in[3];
    const float* bias   = (const float*)d_in[4];
    float*       out    = (float*)d_out;

    const size_t xb_bytes = (size_t)M_TOK * K_DIM * 2;   // 67.1 MB
    const size_t wb_bytes = (size_t)N_OUT * K_DIM * 2;   // 33.6 MB

    if (ws_size >= xb_bytes + wb_bytes) {
        __bf16* xb = (__bf16*)d_ws;
        __bf16* wb = (__bf16*)((char*)d_ws + xb_bytes);
        prep_kernel<<<XBLOCKS + WBLOCKS, 256, 0, stream>>>(x, xb, wq, scales, zeros, wb);
        dim3 grid((M_TOK / 256) * (N_OUT / 256));   // 512 wgs, 1D for XCD swizzle
        gemm_bt256_kernel<<<grid, 512, 0, stream>>>(xb, wb, bias, out);
    } else {
        dim3 grid(M_TOK / 128, N_OUT / 128);
        qlinear_fused_kernel<<<grid, 256, 0, stream>>>(x, wq, scales, zeros, bias, out);
    }
}